// Round 12
// baseline (318.394 us; speedup 1.0000x reference)
//
#include <hip/hip_runtime.h>

// AutoCorrelation attention (Autoformer) for B=16, L=2048, d=512, top_k=7.
// R1: XOR-swizzled GEMM LDS.  R2: FFT rewrite.  R3: 16x16x32 MFMA + XCD
// decode.  R4: f16 Q/K.  R5: merged QK GEMM + reduce_sp.  R6: reverted.
// R7: all-f16 GEMMs.  R8/R9: schedule variants — NEUTRAL (not latency-bound).
// R10: coalesced C epilogue (WIN: stores were 665 GB/s-bound).
// R11: 256x256 tiles (87 -> 131 FLOP per staged LDS byte; per-CU VMEM issue
//      at ~83% ceiling was the GEMM wall) + 32B/thread cvt_inputs.

typedef _Float16 f16;
typedef _Float16 f16x8 __attribute__((ext_vector_type(8)));
typedef _Float16 f16x4 __attribute__((ext_vector_type(4)));
typedef float    f32x4 __attribute__((ext_vector_type(4)));

#define PSI(i) ((i) + ((i) >> 3))          // z anti-conflict pad (2048 -> 2304)
#define TWI(j) ((j) + ((j) >> 4))          // tw anti-conflict pad (1024 -> 1088)

__device__ __forceinline__ float2 f2add(float2 a, float2 b) { return make_float2(a.x + b.x, a.y + b.y); }
__device__ __forceinline__ float2 f2sub(float2 a, float2 b) { return make_float2(a.x - b.x, a.y - b.y); }
__device__ __forceinline__ float2 cmul(float2 a, float2 b)  { return make_float2(a.x * b.x - a.y * b.y, a.x * b.y + a.y * b.x); }

// ---------------- conversions: f32 -> f16 -----------------------------------
// 32B read / 16B write per thread; grid (8192, 3).
__global__ __launch_bounds__(256) void cvt_inputs(
    const float* __restrict__ q, const float* __restrict__ k, const float* __restrict__ v,
    f16* __restrict__ xq, f16* __restrict__ xk, f16* __restrict__ xv)
{
    const float* src = (blockIdx.y == 0) ? q : (blockIdx.y == 1) ? k : v;
    f16*         dst = (blockIdx.y == 0) ? xq : (blockIdx.y == 1) ? xk : xv;
    const int i = blockIdx.x * 256 + threadIdx.x;
    float4 a = ((const float4*)src)[2 * i];
    float4 b = ((const float4*)src)[2 * i + 1];
    f16x8 h = { (f16)a.x, (f16)a.y, (f16)a.z, (f16)a.w,
                (f16)b.x, (f16)b.y, (f16)b.z, (f16)b.w };
    ((f16x8*)dst)[i] = h;
}

__global__ __launch_bounds__(256) void cvt_weights(
    const float* __restrict__ w0, const float* __restrict__ w1,
    const float* __restrict__ w2, const float* __restrict__ w3,
    f16* __restrict__ o0, f16* __restrict__ o1, f16* __restrict__ o2, f16* __restrict__ o3)
{
    const float* src = (blockIdx.y == 0) ? w0 : (blockIdx.y == 1) ? w1 : (blockIdx.y == 2) ? w2 : w3;
    f16*         dst = (blockIdx.y == 0) ? o0 : (blockIdx.y == 1) ? o1 : (blockIdx.y == 2) ? o2 : o3;
    const int i = blockIdx.x * 256 + threadIdx.x;
    float4 val = ((const float4*)src)[i];
    f16x4 h = { (f16)val.x, (f16)val.y, (f16)val.z, (f16)val.w };
    ((f16x4*)dst)[i] = h;
}

// ---------------- GEMM staging: one 64-col K-slab of a 256-row operand ------
// 512 threads, 4 loads/thread; LDS linear (lane-contiguous 16B), global
// source octet pre-swizzled by (row&7) — read side applies the same XOR.
__device__ __forceinline__ void stage_op256(const f16* __restrict__ G, int row0, int k0,
                                            f16* __restrict__ lds, int tid)
{
#pragma unroll
    for (int q = 0; q < 4; ++q) {
        const int r = q * 64 + (tid >> 3);
        const int u = (tid & 7) ^ ((tid >> 3) & 7);
        const f16* g = G + (size_t)(row0 + r) * 512 + k0 + u * 8;
        f16* d = lds + q * 4096 + (tid >> 6) * 512;     // wave-uniform base
        __builtin_amdgcn_global_load_lds(
            (const __attribute__((address_space(1))) void*)g,
            (__attribute__((address_space(3))) void*)d, 16, 0, 0);
    }
}

// ---------------- NT GEMM: C[M,N] = A * B^T (+bias), f16 16x16x32 MFMA ------
// BM = BN = 256, BK = 64, K = 512. 8 waves, per-wave 128x64 output
// (acc[8][4] = 128 VGPR). 2-buffer LDS (128 KB), stage-ahead schedule.
// Epilogue: acc -> XOR-swizzled LDS C tile -> linear 16B/lane stores
// (f32 output in two 128-row chunks).
template<int F16OUT, int MT_L2, int NT_L2, int SWZ, int SPLITB>
__global__ __launch_bounds__(512, 2) void gemm_nt(
    const f16* __restrict__ A0, const f16* __restrict__ B0, const f16* __restrict__ B1,
    void* __restrict__ Cout, int N,
    const float* __restrict__ bias_q, const float* __restrict__ bias_k,
    const float* __restrict__ bias_col)
{
    constexpr int BM = 256, BN = 256, NKT = 8;
    constexpr int ESZ = F16OUT ? 2 : 4;

    __shared__ __align__(16) char smem[131072];         // 2 x (16K A + 16K B) f16
    f16* smA = (f16*)smem;                              // [2][BM*64]
    f16* smB = (f16*)smem + 2 * BM * 64;                // [2][BN*64]

    const int tid  = threadIdx.x;
    const int wave = tid >> 6, lane = tid & 63;

    int mt, nt;
    if (SWZ == 1) {
        const int xcd = blockIdx.x & 7, slot = blockIdx.x >> 3;
        mt = slot & ((1 << MT_L2) - 1);
        nt = (xcd << (NT_L2 - 3)) | (slot >> MT_L2);
    } else if (SWZ == 2) {
        const int xcd = blockIdx.x & 7, slot = blockIdx.x >> 3;
        nt = slot & ((1 << NT_L2) - 1);
        mt = (xcd << (MT_L2 - 3)) | (slot >> NT_L2);
    } else {
        nt = blockIdx.x & ((1 << NT_L2) - 1);
        mt = blockIdx.x >> NT_L2;
    }
    const int m0 = mt * BM, n0 = nt * BN;

    const bool useB1 = SPLITB && (mt >= (1 << (MT_L2 - 1)));
    const f16* Bg = useB1 ? B1 : B0;
    const float* brow = SPLITB
        ? (useB1 ? bias_k - (1 << (MT_L2 - 1)) * BM : bias_q)
        : bias_q;

    f32x4 acc[8][4];
#pragma unroll
    for (int m = 0; m < 8; ++m)
#pragma unroll
        for (int n = 0; n < 4; ++n) acc[m][n] = (f32x4){0.f, 0.f, 0.f, 0.f};

    const int fr = lane & 15;
    const int kg = (lane >> 4) * 8;          // k-group base within 32-wide K step
    const int rowm = fr & 7;                 // read-side swizzle key
    const int wr = wave >> 2;                // wave row (0..1), 128 rows each
    const int wc = wave & 3;                 // wave col (0..3), 64 cols each
    const int warow = wr * 128 + fr;
    const int wbrow = wc * 64 + fr;

    auto compute = [&](const f16* __restrict__ Ab, const f16* __restrict__ Bb) {
#pragma unroll
        for (int k2 = 0; k2 < 2; ++k2) {
            const int kb = k2 * 32 + kg;
            const int col = ((kb >> 3) ^ rowm) << 3;
            f16x8 af[8], bf[4];
#pragma unroll
            for (int m = 0; m < 8; ++m) af[m] = *(const f16x8*)&Ab[(warow + m * 16) * 64 + col];
#pragma unroll
            for (int n = 0; n < 4; ++n) bf[n] = *(const f16x8*)&Bb[(wbrow + n * 16) * 64 + col];
#pragma unroll
            for (int m = 0; m < 8; ++m)
#pragma unroll
                for (int n = 0; n < 4; ++n)
                    acc[m][n] = __builtin_amdgcn_mfma_f32_16x16x32_f16(af[m], bf[n], acc[m][n], 0, 0, 0);
        }
    };

    stage_op256(A0, m0, 0, smA, tid);
    stage_op256(Bg, n0, 0, smB, tid);
    asm volatile("s_waitcnt vmcnt(0)" ::: "memory");
    __builtin_amdgcn_s_barrier();

#pragma unroll 1
    for (int kk = 0; kk < NKT; ++kk) {
        const int cur = kk & 1;
        if (kk < NKT - 1) {
            stage_op256(A0, m0, (kk + 1) * 64, smA + (cur ^ 1) * BM * 64, tid);
            stage_op256(Bg, n0, (kk + 1) * 64, smB + (cur ^ 1) * BN * 64, tid);
        }
        compute(smA + cur * BM * 64, smB + cur * BN * 64);
        asm volatile("s_waitcnt vmcnt(0) lgkmcnt(0)" ::: "memory");
        __builtin_amdgcn_s_barrier();
    }

    // ---- epilogue: acc -> swizzled LDS C tile -> linear 16B stores ----
    constexpr int L     = F16OUT ? 3 : 2;          // elems-per-16B log2
    constexpr int CPR   = (BN * ESZ) / 16;         // 16B chunks per row
    constexpr int HROWS = F16OUT ? 256 : 128;      // rows per epilogue pass
    constexpr int NH    = F16OUT ? 1 : 2;
#pragma unroll 1
    for (int h = 0; h < NH; ++h) {
        __syncthreads();
        if (F16OUT || wr == h) {
            const int lr0 = wr * 128 + ((lane >> 4) << 2);
#pragma unroll
            for (int m = 0; m < 8; ++m)
#pragma unroll
                for (int n = 0; n < 4; ++n) {
                    const int col = wc * 64 + n * 16 + fr;
                    const float bc = bias_col ? bias_col[n0 + col] : 0.f;
#pragma unroll
                    for (int j = 0; j < 4; ++j) {
                        const int row  = lr0 + m * 16 + j;
                        const int rl   = row - h * HROWS * (F16OUT ? 0 : 1);
                        const int scol = ((((col >> L) ^ (row & 7)) << L) | (col & ((1 << L) - 1)));
                        float v = acc[m][n][j] + bc + (brow ? brow[m0 + row] : 0.f);
                        if (F16OUT) ((f16*)smem)[row * BN + scol] = (f16)v;
                        else        ((float*)smem)[rl * BN + scol] = v;
                    }
                }
        }
        __syncthreads();
        const int chunks = HROWS * CPR;
#pragma unroll 1
        for (int i = tid; i < chunks; i += 512) {
            const int rl  = i / CPR;
            const int u   = i % CPR;
            const int row = h * HROWS + rl;
            int4 vv = *(const int4*)(smem + (rl * CPR + (u ^ (row & 7))) * 16);
            *(int4*)((char*)Cout + ((size_t)(m0 + row) * N + n0) * ESZ + u * 16) = vv;
        }
    }
}

// ---------------- 2048-pt FFT: fused double radix-2 DIF passes --------------
template<int S>
__device__ __forceinline__ void fft_pass2(float2* __restrict__ z, const float2* __restrict__ tw, int tid)
{
    constexpr int m = 1024 >> S;
    constexpr int h = m >> 1;
#pragma unroll
    for (int rep = 0; rep < 2; ++rep) {
        const int idx = tid + rep * 256;
        const int j2  = idx & (h - 1);
        const int blk = idx >> (9 - S);
        const int i   = (blk << (11 - S)) + j2;
        const float2 w1 = tw[TWI(j2 << S)];
        const float2 w2 = tw[TWI(j2 << (S + 1))];
        float2 a = z[PSI(i)], b = z[PSI(i + h)], c = z[PSI(i + m)], d = z[PSI(i + m + h)];
        float2 a1 = f2add(a, c);
        float2 c1 = cmul(f2sub(a, c), w1);
        float2 b1 = f2add(b, d);
        float2 t0 = cmul(f2sub(b, d), w1);
        float2 d1 = make_float2(t0.y, -t0.x);            // * (-i)  (w_{j+h} = -i*w_j)
        z[PSI(i)]         = f2add(a1, b1);
        z[PSI(i + h)]     = cmul(f2sub(a1, b1), w2);
        z[PSI(i + m)]     = f2add(c1, d1);
        z[PSI(i + m + h)] = cmul(f2sub(c1, d1), w2);
    }
    __syncthreads();
}

__device__ __forceinline__ void fft_tail_scatter(float2* __restrict__ z, int tid)
{
    float2 v[8];
    const int p0 = tid * 8;
#pragma unroll
    for (int e = 0; e < 8; ++e) v[e] = z[PSI(p0 + e)];
    __syncthreads();
    constexpr float RS = 0.70710678118654752f;
    const float2 W8[4] = { {1.f, 0.f}, {RS, -RS}, {0.f, -1.f}, {-RS, -RS} };
#pragma unroll
    for (int e = 0; e < 4; ++e) {
        float2 t = f2sub(v[e], v[e + 4]);
        v[e]     = f2add(v[e], v[e + 4]);
        v[e + 4] = cmul(t, W8[e]);
    }
#pragma unroll
    for (int base = 0; base < 8; base += 4) {
        float2 t0 = f2sub(v[base], v[base + 2]);
        v[base]     = f2add(v[base], v[base + 2]);
        v[base + 2] = t0;
        float2 t1 = f2sub(v[base + 1], v[base + 3]);
        v[base + 1] = f2add(v[base + 1], v[base + 3]);
        v[base + 3] = make_float2(t1.y, -t1.x);
    }
#pragma unroll
    for (int base = 0; base < 8; base += 2) {
        float2 t = f2sub(v[base], v[base + 1]);
        v[base]     = f2add(v[base], v[base + 1]);
        v[base + 1] = t;
    }
    const int br8t = (int)(__brev((unsigned)tid) >> 24);
    const int BR3[8] = {0, 4, 2, 6, 1, 5, 3, 7};
#pragma unroll
    for (int e = 0; e < 8; ++e) {
        const int f = br8t + (BR3[e] << 8);
        z[PSI(f)] = v[e];
    }
    __syncthreads();
}

__device__ __forceinline__ void fft2048_natural(float2* __restrict__ z, const float2* __restrict__ tw, int tid)
{
    fft_pass2<0>(z, tw, tid);
    fft_pass2<2>(z, tw, tid);
    fft_pass2<4>(z, tw, tid);
    fft_pass2<6>(z, tw, tid);
    fft_tail_scatter(z, tid);   // z now holds Z[f] at natural f (PSI-mapped)
}

__device__ __forceinline__ void fill_tw(float2* __restrict__ tw, int tid)
{
    for (int j = tid; j < 1024; j += 256) {
        float sv, cv;
        sincospif(-(float)j * (1.0f / 1024.0f), &sv, &cv);   // e^{-2 pi i j / 2048}
        tw[TWI(j)] = make_float2(cv, sv);
    }
}

// 8 channels/block: z = q + i*k packed FFT; S_c = Q*conj(K) accumulated in
// registers over channels; Hermitian half f=0..1024 written to Sp.
__global__ __launch_bounds__(256) void fft_corr(
    const f16* __restrict__ Qt, const f16* __restrict__ Kt,
    float2* __restrict__ Sp)
{
    __shared__ float2 z[2304];
    __shared__ float2 tw[1088];
    const int tid = threadIdx.x;
    const int grp = blockIdx.x;   // 0..63 channel group (8 ch each)
    const int b   = blockIdx.y;   // 0..15 batch

    fill_tw(tw, tid);
    float2 racc[5];
#pragma unroll
    for (int r = 0; r < 5; ++r) racc[r] = make_float2(0.f, 0.f);
    __syncthreads();

    for (int ch = 0; ch < 8; ++ch) {
        const int c = grp * 8 + ch;
        const f16x8* qr = (const f16x8*)(Qt + ((size_t)c * 16 + b) * 2048);
        const f16x8* kr = (const f16x8*)(Kt + ((size_t)c * 16 + b) * 2048);
        f16x8 qv = qr[tid], kv = kr[tid];
        const int e0 = tid * 8;
#pragma unroll
        for (int j = 0; j < 8; ++j)
            z[PSI(e0 + j)] = make_float2((float)qv[j], (float)kv[j]);
        __syncthreads();
        fft2048_natural(z, tw, tid);
#pragma unroll
        for (int r = 0; r < 5; ++r) {
            const int f = tid + (r << 8);
            if (f <= 1024) {
                const int pf = (2048 - f) & 2047;
                float2 Zf  = z[PSI(f)];
                float2 Zc0 = z[PSI(pf)];
                float qx = 0.5f * (Zf.x + Zc0.x), qy = 0.5f * (Zf.y - Zc0.y);
                float dx = Zf.x - Zc0.x,          dy = Zf.y + Zc0.y;
                float kx = 0.5f * dy,             ky = -0.5f * dx;   // K = -i*D/2
                racc[r].x += qx * kx + qy * ky;                      // Q*conj(K)
                racc[r].y += qy * kx - qx * ky;
            }
        }
        __syncthreads();
    }
    float2* out = Sp + ((size_t)b * 64 + grp) * 1025;
#pragma unroll
    for (int r = 0; r < 5; ++r) {
        const int f = tid + (r << 8);
        if (f <= 1024) out[f] = racc[r];
    }
}

// fixed-order sum of the 64 per-group spectra -> Sred[b][f]
__global__ __launch_bounds__(256) void reduce_sp(
    const float2* __restrict__ Sp, float2* __restrict__ Sred)
{
    const int b = blockIdx.x;
    const int f = blockIdx.y * 256 + threadIdx.x;
    if (f > 1024) return;
    const float2* base = Sp + (size_t)b * 64 * 1025 + f;
    float sx = 0.f, sy = 0.f;
#pragma unroll 8
    for (int g = 0; g < 64; ++g) {
        float2 p = base[(size_t)g * 1025];
        sx += p.x; sy += p.y;
    }
    Sred[b * 1025 + f] = make_float2(sx, sy);
}

// rebuild full spectrum from Hermitian half, inverse FFT via conj trick
// (same natural-order forward FFT), write mean_value.
__global__ __launch_bounds__(256) void ifft_mean(
    const float2* __restrict__ Sred, float* __restrict__ mv)
{
    __shared__ float2 z[2304];
    __shared__ float2 tw[1088];
    const int tid = threadIdx.x;
    const int b   = blockIdx.x;
    fill_tw(tw, tid);
#pragma unroll
    for (int r = 0; r < 5; ++r) {
        const int f = tid + (r << 8);
        if (f <= 1024) {
            float2 s = Sred[b * 1025 + f];
            z[PSI(f)] = make_float2(s.x, -s.y);                     // conj(S[f])
            if (f >= 1 && f <= 1023)
                z[PSI(2048 - f)] = make_float2(s.x, s.y);           // conj(S[2048-f]) = S[f]
        }
    }
    __syncthreads();
    fft2048_natural(z, tw, tid);
    const float scale = 1.0f / (2048.0f * 512.0f);  // irfft 1/N and channel mean
    for (int t = tid; t < 2048; t += 256)
        mv[(size_t)b * 2048 + t] = z[PSI(t)].x * scale;
}

// top-7 lags of batch-mean corr + per-batch softmax weights. One block.
__global__ __launch_bounds__(256) void select_topk(
    const float* __restrict__ mv, int* __restrict__ sel, float* __restrict__ wsm)
{
    __shared__ float u[2048];
    __shared__ float rv[256];
    __shared__ int   ri[256];
    __shared__ int   ssel[7];
    const int tid = threadIdx.x;
    for (int t = tid; t < 2048; t += 256) {
        float s = 0.f;
        for (int b = 0; b < 16; ++b) s += mv[b * 2048 + t];
        u[t] = s;
    }
    __syncthreads();
    for (int k = 0; k < 7; ++k) {
        float best = -3.4e38f; int bi = 0x7fffffff;
        for (int t = tid; t < 2048; t += 256)
            if (u[t] > best) { best = u[t]; bi = t; }
        rv[tid] = best; ri[tid] = bi;
        __syncthreads();
        for (int off = 128; off > 0; off >>= 1) {
            if (tid < off) {
                if (rv[tid + off] > rv[tid] ||
                    (rv[tid + off] == rv[tid] && ri[tid + off] < ri[tid])) {
                    rv[tid] = rv[tid + off]; ri[tid] = ri[tid + off];
                }
            }
            __syncthreads();
        }
        if (tid == 0) { ssel[k] = ri[0]; sel[k] = ri[0]; u[ri[0]] = -3.4e38f; }
        __syncthreads();
    }
    if (tid < 16) {
        float vals[7], mx = -3.4e38f;
        for (int k = 0; k < 7; ++k) { vals[k] = mv[tid * 2048 + ssel[k]]; mx = fmaxf(mx, vals[k]); }
        float se = 0.f;
        for (int k = 0; k < 7; ++k) { vals[k] = expf(vals[k] - mx); se += vals[k]; }
        for (int k = 0; k < 7; ++k) wsm[tid * 7 + k] = vals[k] / se;
    }
}

// agg[b,l,c] = sum_k w[b,k] * V[b,(l+sel[k])%L,c]
__global__ __launch_bounds__(256) void aggregate(
    const f16* __restrict__ V, const int* __restrict__ sel,
    const float* __restrict__ wsm, f16* __restrict__ agg)
{
    __shared__ int   sidx[7];
    __shared__ float sw[7];
    const int bl = blockIdx.x;
    const int b = bl >> 11, l = bl & 2047;
    if (threadIdx.x < 7) { sidx[threadIdx.x] = sel[threadIdx.x]; sw[threadIdx.x] = wsm[b * 7 + threadIdx.x]; }
    __syncthreads();
    const int c = threadIdx.x;
    float a0 = 0.f, a1 = 0.f;
#pragma unroll
    for (int k = 0; k < 7; ++k) {
        const int lk = (l + sidx[k]) & 2047;
        const f16* row = V + ((size_t)b * 2048 + lk) * 512;
        a0 += sw[k] * (float)row[c];
        a1 += sw[k] * (float)row[c + 256];
    }
    f16* orow = agg + ((size_t)b * 2048 + l) * 512;
    orow[c]       = (f16)a0;
    orow[c + 256] = (f16)a1;
}

extern "C" void kernel_launch(void* const* d_in, const int* in_sizes, int n_in,
                              void* d_out, int out_size, void* d_ws, size_t ws_size,
                              hipStream_t stream)
{
    (void)in_sizes; (void)n_in; (void)out_size; (void)ws_size;
    const float* queries = (const float*)d_in[0];
    const float* keys    = (const float*)d_in[1];
    const float* values  = (const float*)d_in[2];
    const float* Wq = (const float*)d_in[3];
    const float* bq = (const float*)d_in[4];
    const float* Wk = (const float*)d_in[5];
    const float* bk = (const float*)d_in[6];
    const float* Wv = (const float*)d_in[7];
    const float* bv = (const float*)d_in[8];
    const float* Wo = (const float*)d_in[9];
    const float* bo = (const float*)d_in[10];

    char* p = (char*)d_ws;
    f16*    Xq  = (f16*)p;    p += 33554432;   // queries f16 [32768][512]
    f16*    Xk  = (f16*)p;    p += 33554432;   // keys    f16
    f16*    Xv  = (f16*)p;    p += 33554432;   // values  f16
    f16*    QKt = (f16*)p;    p += 67108864;   // [1024][32768] f16: Q rows 0..511, K rows 512..1023
    f16*    Vb  = (f16*)p;    p += 33554432;   // V (b, l, c) f16
    f16*    agg = (f16*)p;    p += 33554432;   // aggregated V, f16
    f16*    wqh = (f16*)p;    p += 524288;     // Wq f16  (wqh+wkh = stacked Wqk, M=1024)
    f16*    wkh = (f16*)p;    p += 524288;     // Wk f16  (MUST stay adjacent to wqh)
    f16*    wvh = (f16*)p;    p += 524288;
    f16*    woh = (f16*)p;    p += 524288;
    float2* Sp  = (float2*)p; p += 8396800;    // 16 x 64 x 1025 cplx partials
    float2* Srd = (float2*)p; p += 131200;     // 16 x 1025 cplx reduced
    float*  mv  = (float*)p;  p += 131072;     // mean_value 16 x 2048
    int*    sel = (int*)p;    p += 256;        // top-7 lags
    float*  wsm = (float*)p;  p += 512;        // softmax weights 16 x 7
    f16*    Kt  = QKt + (size_t)512 * 32768;

    // conversions: 4 weights (one dispatch), 3 inputs (one dispatch)
    cvt_weights<<<dim3(256, 4), 256, 0, stream>>>(Wq, Wk, Wv, Wo, wqh, wkh, wvh, woh);
    cvt_inputs<<<dim3(8192, 3), 256, 0, stream>>>(queries, keys, values, Xq, Xk, Xv);

    // QK^T = [Wq;Wk] * X^T, X = Xq (mt<2) / Xk (mt>=2), all f16.
    // M=1024 (4 mt), N=32768 (128 nt): 512 blocks.
    gemm_nt<1, 2, 7, 1, 1><<<512, 512, 0, stream>>>(
        wqh, Xq, Xk, QKt, 32768, bq, bk, nullptr);

    // V = Xv @ Wv^T, f16 out (b,l,c), +bv. M=32768 (128 mt), N=512 (2 nt): 256 blocks.
    gemm_nt<1, 7, 1, 2, 0><<<256, 512, 0, stream>>>(
        Xv, wvh, nullptr, Vb, 512, nullptr, nullptr, bv);

    // correlation spectra -> reduce -> mean_value -> selection -> aggregation
    fft_corr<<<dim3(64, 16), 256, 0, stream>>>(QKt, Kt, Sp);
    reduce_sp<<<dim3(16, 5), 256, 0, stream>>>(Sp, Srd);
    ifft_mean<<<16, 256, 0, stream>>>(Srd, mv);
    select_topk<<<1, 256, 0, stream>>>(mv, sel, wsm);
    aggregate<<<32768, 256, 0, stream>>>(Vb, sel, wsm, agg);

    // out = agg @ Wo^T + bo  -> d_out f32
    gemm_nt<0, 7, 1, 2, 0><<<256, 512, 0, stream>>>(
        agg, woh, nullptr, (float*)d_out, 512, nullptr, nullptr, bo);
}

// Round 13
// 285.700 us; speedup vs baseline: 1.1144x; 1.1144x over previous
//
#include <hip/hip_runtime.h>

// AutoCorrelation attention (Autoformer) for B=16, L=2048, d=512, top_k=7.
// R1: XOR-swizzled GEMM LDS.  R2: FFT rewrite.  R3: 16x16x32 MFMA + XCD
// decode.  R4: f16 Q/K.  R5: merged QK GEMM + reduce_sp.  R6: reverted.
// R7: all-f16 GEMMs.  R8/R9: schedule variants — NEUTRAL.
// R10: coalesced C epilogue (WIN).  R11: 256x256 tiles.
// R12: cvt_inputs ELIMINATED — f32 operands consumed directly by the GEMMs
//      via convert-once reg-staging (global f32 -> reg -> cvt -> swizzled
//      ds_write, T14 issue-early/write-late). cvt_inputs was at its own
//      480MB roofline (~80 us); R6's failure was convert-per-USE, not -once.

typedef _Float16 f16;
typedef _Float16 f16x8 __attribute__((ext_vector_type(8)));
typedef _Float16 f16x4 __attribute__((ext_vector_type(4)));
typedef float    f32x4 __attribute__((ext_vector_type(4)));

#define PSI(i) ((i) + ((i) >> 3))          // z anti-conflict pad (2048 -> 2304)
#define TWI(j) ((j) + ((j) >> 4))          // tw anti-conflict pad (1024 -> 1088)

__device__ __forceinline__ float2 f2add(float2 a, float2 b) { return make_float2(a.x + b.x, a.y + b.y); }
__device__ __forceinline__ float2 f2sub(float2 a, float2 b) { return make_float2(a.x - b.x, a.y - b.y); }
__device__ __forceinline__ float2 cmul(float2 a, float2 b)  { return make_float2(a.x * b.x - a.y * b.y, a.x * b.y + a.y * b.x); }

// ---------------- conversion: f32 -> f16 (weights only) ---------------------
__global__ __launch_bounds__(256) void cvt_weights(
    const float* __restrict__ w0, const float* __restrict__ w1,
    const float* __restrict__ w2, const float* __restrict__ w3,
    f16* __restrict__ o0, f16* __restrict__ o1, f16* __restrict__ o2, f16* __restrict__ o3)
{
    const float* src = (blockIdx.y == 0) ? w0 : (blockIdx.y == 1) ? w1 : (blockIdx.y == 2) ? w2 : w3;
    f16*         dst = (blockIdx.y == 0) ? o0 : (blockIdx.y == 1) ? o1 : (blockIdx.y == 2) ? o2 : o3;
    const int i = blockIdx.x * 256 + threadIdx.x;
    float4 val = ((const float4*)src)[i];
    f16x4 h = { (f16)val.x, (f16)val.y, (f16)val.z, (f16)val.w };
    ((f16x4*)dst)[i] = h;
}

// ---------------- GEMM staging ----------------------------------------------
// LDS image per 256-row x 64-col slab (32 KB f16): LDS[rr][uu] holds global
// 8-elem octet (uu ^ (rr&7)) of row rr — read side XORs the same key.
//
// f16 source: global_load_lds, pre-swizzled global octet, linear LDS dest.
__device__ __forceinline__ void stage_f16(const f16* __restrict__ G, int row0, int k0,
                                          f16* __restrict__ lds, int tid)
{
#pragma unroll
    for (int q = 0; q < 4; ++q) {
        const int r = q * 64 + (tid >> 3);
        const int u = (tid & 7) ^ ((tid >> 3) & 7);
        const f16* g = G + (size_t)(row0 + r) * 512 + k0 + u * 8;
        f16* d = lds + q * 4096 + (tid >> 6) * 512;     // wave-uniform base
        __builtin_amdgcn_global_load_lds(
            (const __attribute__((address_space(1))) void*)g,
            (__attribute__((address_space(3))) void*)d, 16, 0, 0);
    }
}

// f32 source, step 1: contiguous 32B/thread loads into regs (8 float4).
__device__ __forceinline__ void load_f32_slab(const float* __restrict__ G, int row0, int k0,
                                              int tid, float4* __restrict__ rg)
{
#pragma unroll
    for (int q = 0; q < 4; ++q) {
        const float* g = G + (size_t)(row0 + q * 64 + (tid >> 3)) * 512 + k0 + (tid & 7) * 8;
        rg[2 * q]     = *(const float4*)g;
        rg[2 * q + 1] = *(const float4*)(g + 4);
    }
}
// f32 source, step 2 (after compute): cvt once + swizzled ds_write_b128.
__device__ __forceinline__ void write_f16_slab(f16* __restrict__ lds, int tid,
                                               const float4* __restrict__ rg)
{
#pragma unroll
    for (int q = 0; q < 4; ++q) {
        float4 a = rg[2 * q], b = rg[2 * q + 1];
        f16x8 h = { (f16)a.x, (f16)a.y, (f16)a.z, (f16)a.w,
                    (f16)b.x, (f16)b.y, (f16)b.z, (f16)b.w };
        const int uu = (tid & 7) ^ ((tid >> 3) & 7);
        *(f16x8*)(lds + q * 4096 + (tid >> 3) * 64 + (uu << 3)) = h;
    }
}

// ---------------- NT GEMM: C[M,N] = A * B^T (+bias), f16 16x16x32 MFMA ------
// BM = BN = 256, BK = 64, K = 512. 8 waves, per-wave 128x64 output.
// 2-buffer LDS (128 KB), stage-ahead schedule; f32 operands reg-staged with
// issue-early / cvt+write-late. Coalesced swizzled-LDS epilogue (R10/R11).
template<int AF32, int BF32, int F16OUT, int MT_L2, int NT_L2, int SWZ, int SPLITB>
__global__ __launch_bounds__(512, 2) void gemm_nt(
    const void* __restrict__ A0v, const void* __restrict__ B0v, const void* __restrict__ B1v,
    void* __restrict__ Cout, int N,
    const float* __restrict__ bias_q, const float* __restrict__ bias_k,
    const float* __restrict__ bias_col)
{
    constexpr int BM = 256, BN = 256, NKT = 8;
    constexpr int ESZ = F16OUT ? 2 : 4;

    __shared__ __align__(16) char smem[131072];         // 2 x (32K A + 32K B) f16
    f16* smA = (f16*)smem;                              // [2][BM*64]
    f16* smB = (f16*)smem + 2 * BM * 64;                // [2][BN*64]

    const int tid  = threadIdx.x;
    const int wave = tid >> 6, lane = tid & 63;

    int mt, nt;
    if (SWZ == 1) {
        const int xcd = blockIdx.x & 7, slot = blockIdx.x >> 3;
        mt = slot & ((1 << MT_L2) - 1);
        nt = (xcd << (NT_L2 - 3)) | (slot >> MT_L2);
    } else if (SWZ == 2) {
        const int xcd = blockIdx.x & 7, slot = blockIdx.x >> 3;
        nt = slot & ((1 << NT_L2) - 1);
        mt = (xcd << (MT_L2 - 3)) | (slot >> NT_L2);
    } else {
        nt = blockIdx.x & ((1 << NT_L2) - 1);
        mt = blockIdx.x >> NT_L2;
    }
    const int m0 = mt * BM, n0 = nt * BN;

    const bool useB1 = SPLITB && (mt >= (1 << (MT_L2 - 1)));
    const void* Bgv = useB1 ? B1v : B0v;
    const float* brow = SPLITB
        ? (useB1 ? bias_k - (1 << (MT_L2 - 1)) * BM : bias_q)
        : bias_q;

    const f16*   Ah = (const f16*)A0v;
    const float* Af = (const float*)A0v;
    const f16*   Bh = (const f16*)Bgv;
    const float* Bf = (const float*)Bgv;

    f32x4 acc[8][4];
#pragma unroll
    for (int m = 0; m < 8; ++m)
#pragma unroll
        for (int n = 0; n < 4; ++n) acc[m][n] = (f32x4){0.f, 0.f, 0.f, 0.f};

    const int fr = lane & 15;
    const int kg = (lane >> 4) * 8;          // k-group base within 32-wide K step
    const int rowm = fr & 7;                 // read-side swizzle key
    const int wr = wave >> 2;                // wave row (0..1), 128 rows each
    const int wc = wave & 3;                 // wave col (0..3), 64 cols each
    const int warow = wr * 128 + fr;
    const int wbrow = wc * 64 + fr;

    auto compute = [&](const f16* __restrict__ Ab, const f16* __restrict__ Bb) {
#pragma unroll
        for (int k2 = 0; k2 < 2; ++k2) {
            const int kb = k2 * 32 + kg;
            const int col = ((kb >> 3) ^ rowm) << 3;
            f16x8 af[8], bf[4];
#pragma unroll
            for (int m = 0; m < 8; ++m) af[m] = *(const f16x8*)&Ab[(warow + m * 16) * 64 + col];
#pragma unroll
            for (int n = 0; n < 4; ++n) bf[n] = *(const f16x8*)&Bb[(wbrow + n * 16) * 64 + col];
#pragma unroll
            for (int m = 0; m < 8; ++m)
#pragma unroll
                for (int n = 0; n < 4; ++n)
                    acc[m][n] = __builtin_amdgcn_mfma_f32_16x16x32_f16(af[m], bf[n], acc[m][n], 0, 0, 0);
        }
    };

    float4 ra[8], rb[8];

    // prologue: slab 0 staged completely (f32 latency exposed once)
    if (AF32) { load_f32_slab(Af, m0, 0, tid, ra); write_f16_slab(smA, tid, ra); }
    else      stage_f16(Ah, m0, 0, smA, tid);
    if (BF32) { load_f32_slab(Bf, n0, 0, tid, rb); write_f16_slab(smB, tid, rb); }
    else      stage_f16(Bh, n0, 0, smB, tid);
    asm volatile("s_waitcnt vmcnt(0) lgkmcnt(0)" ::: "memory");
    __builtin_amdgcn_s_barrier();

#pragma unroll 1
    for (int kk = 0; kk < NKT; ++kk) {
        const int cur = kk & 1;
        if (kk < NKT - 1) {
            const int k0 = (kk + 1) * 64;
            if (AF32) load_f32_slab(Af, m0, k0, tid, ra);       // issue early
            else      stage_f16(Ah, m0, k0, smA + (cur ^ 1) * BM * 64, tid);
            if (BF32) load_f32_slab(Bf, n0, k0, tid, rb);
            else      stage_f16(Bh, n0, k0, smB + (cur ^ 1) * BN * 64, tid);
        }
        compute(smA + cur * BM * 64, smB + cur * BN * 64);       // hides f32 latency
        if (kk < NKT - 1) {
            if (AF32) write_f16_slab(smA + (cur ^ 1) * BM * 64, tid, ra);   // write late
            if (BF32) write_f16_slab(smB + (cur ^ 1) * BN * 64, tid, rb);
        }
        asm volatile("s_waitcnt vmcnt(0) lgkmcnt(0)" ::: "memory");
        __builtin_amdgcn_s_barrier();
    }

    // ---- epilogue: acc -> swizzled LDS C tile -> linear 16B stores ----
    constexpr int L     = F16OUT ? 3 : 2;          // elems-per-16B log2
    constexpr int CPR   = (BN * ESZ) / 16;         // 16B chunks per row
    constexpr int HROWS = F16OUT ? 256 : 128;      // rows per epilogue pass
    constexpr int NH    = F16OUT ? 1 : 2;
#pragma unroll 1
    for (int h = 0; h < NH; ++h) {
        __syncthreads();
        if (F16OUT || wr == h) {
            const int lr0 = wr * 128 + ((lane >> 4) << 2);
#pragma unroll
            for (int m = 0; m < 8; ++m)
#pragma unroll
                for (int n = 0; n < 4; ++n) {
                    const int col = wc * 64 + n * 16 + fr;
                    const float bc = bias_col ? bias_col[n0 + col] : 0.f;
#pragma unroll
                    for (int j = 0; j < 4; ++j) {
                        const int row  = lr0 + m * 16 + j;
                        const int rl   = row - h * HROWS * (F16OUT ? 0 : 1);
                        const int scol = ((((col >> L) ^ (row & 7)) << L) | (col & ((1 << L) - 1)));
                        float v = acc[m][n][j] + bc + (brow ? brow[m0 + row] : 0.f);
                        if (F16OUT) ((f16*)smem)[row * BN + scol] = (f16)v;
                        else        ((float*)smem)[rl * BN + scol] = v;
                    }
                }
        }
        __syncthreads();
        const int chunks = HROWS * CPR;
#pragma unroll 1
        for (int i = tid; i < chunks; i += 512) {
            const int rl  = i / CPR;
            const int u   = i % CPR;
            const int row = h * HROWS + rl;
            int4 vv = *(const int4*)(smem + (rl * CPR + (u ^ (row & 7))) * 16);
            *(int4*)((char*)Cout + ((size_t)(m0 + row) * N + n0) * ESZ + u * 16) = vv;
        }
    }
}

// ---------------- 2048-pt FFT: fused double radix-2 DIF passes --------------
template<int S>
__device__ __forceinline__ void fft_pass2(float2* __restrict__ z, const float2* __restrict__ tw, int tid)
{
    constexpr int m = 1024 >> S;
    constexpr int h = m >> 1;
#pragma unroll
    for (int rep = 0; rep < 2; ++rep) {
        const int idx = tid + rep * 256;
        const int j2  = idx & (h - 1);
        const int blk = idx >> (9 - S);
        const int i   = (blk << (11 - S)) + j2;
        const float2 w1 = tw[TWI(j2 << S)];
        const float2 w2 = tw[TWI(j2 << (S + 1))];
        float2 a = z[PSI(i)], b = z[PSI(i + h)], c = z[PSI(i + m)], d = z[PSI(i + m + h)];
        float2 a1 = f2add(a, c);
        float2 c1 = cmul(f2sub(a, c), w1);
        float2 b1 = f2add(b, d);
        float2 t0 = cmul(f2sub(b, d), w1);
        float2 d1 = make_float2(t0.y, -t0.x);            // * (-i)  (w_{j+h} = -i*w_j)
        z[PSI(i)]         = f2add(a1, b1);
        z[PSI(i + h)]     = cmul(f2sub(a1, b1), w2);
        z[PSI(i + m)]     = f2add(c1, d1);
        z[PSI(i + m + h)] = cmul(f2sub(c1, d1), w2);
    }
    __syncthreads();
}

__device__ __forceinline__ void fft_tail_scatter(float2* __restrict__ z, int tid)
{
    float2 v[8];
    const int p0 = tid * 8;
#pragma unroll
    for (int e = 0; e < 8; ++e) v[e] = z[PSI(p0 + e)];
    __syncthreads();
    constexpr float RS = 0.70710678118654752f;
    const float2 W8[4] = { {1.f, 0.f}, {RS, -RS}, {0.f, -1.f}, {-RS, -RS} };
#pragma unroll
    for (int e = 0; e < 4; ++e) {
        float2 t = f2sub(v[e], v[e + 4]);
        v[e]     = f2add(v[e], v[e + 4]);
        v[e + 4] = cmul(t, W8[e]);
    }
#pragma unroll
    for (int base = 0; base < 8; base += 4) {
        float2 t0 = f2sub(v[base], v[base + 2]);
        v[base]     = f2add(v[base], v[base + 2]);
        v[base + 2] = t0;
        float2 t1 = f2sub(v[base + 1], v[base + 3]);
        v[base + 1] = f2add(v[base + 1], v[base + 3]);
        v[base + 3] = make_float2(t1.y, -t1.x);
    }
#pragma unroll
    for (int base = 0; base < 8; base += 2) {
        float2 t = f2sub(v[base], v[base + 1]);
        v[base]     = f2add(v[base], v[base + 1]);
        v[base + 1] = t;
    }
    const int br8t = (int)(__brev((unsigned)tid) >> 24);
    const int BR3[8] = {0, 4, 2, 6, 1, 5, 3, 7};
#pragma unroll
    for (int e = 0; e < 8; ++e) {
        const int f = br8t + (BR3[e] << 8);
        z[PSI(f)] = v[e];
    }
    __syncthreads();
}

__device__ __forceinline__ void fft2048_natural(float2* __restrict__ z, const float2* __restrict__ tw, int tid)
{
    fft_pass2<0>(z, tw, tid);
    fft_pass2<2>(z, tw, tid);
    fft_pass2<4>(z, tw, tid);
    fft_pass2<6>(z, tw, tid);
    fft_tail_scatter(z, tid);   // z now holds Z[f] at natural f (PSI-mapped)
}

__device__ __forceinline__ void fill_tw(float2* __restrict__ tw, int tid)
{
    for (int j = tid; j < 1024; j += 256) {
        float sv, cv;
        sincospif(-(float)j * (1.0f / 1024.0f), &sv, &cv);   // e^{-2 pi i j / 2048}
        tw[TWI(j)] = make_float2(cv, sv);
    }
}

// 8 channels/block: z = q + i*k packed FFT; S_c = Q*conj(K) accumulated in
// registers over channels; Hermitian half f=0..1024 written to Sp.
__global__ __launch_bounds__(256) void fft_corr(
    const f16* __restrict__ Qt, const f16* __restrict__ Kt,
    float2* __restrict__ Sp)
{
    __shared__ float2 z[2304];
    __shared__ float2 tw[1088];
    const int tid = threadIdx.x;
    const int grp = blockIdx.x;   // 0..63 channel group (8 ch each)
    const int b   = blockIdx.y;   // 0..15 batch

    fill_tw(tw, tid);
    float2 racc[5];
#pragma unroll
    for (int r = 0; r < 5; ++r) racc[r] = make_float2(0.f, 0.f);
    __syncthreads();

    for (int ch = 0; ch < 8; ++ch) {
        const int c = grp * 8 + ch;
        const f16x8* qr = (const f16x8*)(Qt + ((size_t)c * 16 + b) * 2048);
        const f16x8* kr = (const f16x8*)(Kt + ((size_t)c * 16 + b) * 2048);
        f16x8 qv = qr[tid], kv = kr[tid];
        const int e0 = tid * 8;
#pragma unroll
        for (int j = 0; j < 8; ++j)
            z[PSI(e0 + j)] = make_float2((float)qv[j], (float)kv[j]);
        __syncthreads();
        fft2048_natural(z, tw, tid);
#pragma unroll
        for (int r = 0; r < 5; ++r) {
            const int f = tid + (r << 8);
            if (f <= 1024) {
                const int pf = (2048 - f) & 2047;
                float2 Zf  = z[PSI(f)];
                float2 Zc0 = z[PSI(pf)];
                float qx = 0.5f * (Zf.x + Zc0.x), qy = 0.5f * (Zf.y - Zc0.y);
                float dx = Zf.x - Zc0.x,          dy = Zf.y + Zc0.y;
                float kx = 0.5f * dy,             ky = -0.5f * dx;   // K = -i*D/2
                racc[r].x += qx * kx + qy * ky;                      // Q*conj(K)
                racc[r].y += qy * kx - qx * ky;
            }
        }
        __syncthreads();
    }
    float2* out = Sp + ((size_t)b * 64 + grp) * 1025;
#pragma unroll
    for (int r = 0; r < 5; ++r) {
        const int f = tid + (r << 8);
        if (f <= 1024) out[f] = racc[r];
    }
}

// fixed-order sum of the 64 per-group spectra -> Sred[b][f]
__global__ __launch_bounds__(256) void reduce_sp(
    const float2* __restrict__ Sp, float2* __restrict__ Sred)
{
    const int b = blockIdx.x;
    const int f = blockIdx.y * 256 + threadIdx.x;
    if (f > 1024) return;
    const float2* base = Sp + (size_t)b * 64 * 1025 + f;
    float sx = 0.f, sy = 0.f;
#pragma unroll 8
    for (int g = 0; g < 64; ++g) {
        float2 p = base[(size_t)g * 1025];
        sx += p.x; sy += p.y;
    }
    Sred[b * 1025 + f] = make_float2(sx, sy);
}

// rebuild full spectrum from Hermitian half, inverse FFT via conj trick
// (same natural-order forward FFT), write mean_value.
__global__ __launch_bounds__(256) void ifft_mean(
    const float2* __restrict__ Sred, float* __restrict__ mv)
{
    __shared__ float2 z[2304];
    __shared__ float2 tw[1088];
    const int tid = threadIdx.x;
    const int b   = blockIdx.x;
    fill_tw(tw, tid);
#pragma unroll
    for (int r = 0; r < 5; ++r) {
        const int f = tid + (r << 8);
        if (f <= 1024) {
            float2 s = Sred[b * 1025 + f];
            z[PSI(f)] = make_float2(s.x, -s.y);                     // conj(S[f])
            if (f >= 1 && f <= 1023)
                z[PSI(2048 - f)] = make_float2(s.x, s.y);           // conj(S[2048-f]) = S[f]
        }
    }
    __syncthreads();
    fft2048_natural(z, tw, tid);
    const float scale = 1.0f / (2048.0f * 512.0f);  // irfft 1/N and channel mean
    for (int t = tid; t < 2048; t += 256)
        mv[(size_t)b * 2048 + t] = z[PSI(t)].x * scale;
}

// top-7 lags of batch-mean corr + per-batch softmax weights. One block.
__global__ __launch_bounds__(256) void select_topk(
    const float* __restrict__ mv, int* __restrict__ sel, float* __restrict__ wsm)
{
    __shared__ float u[2048];
    __shared__ float rv[256];
    __shared__ int   ri[256];
    __shared__ int   ssel[7];
    const int tid = threadIdx.x;
    for (int t = tid; t < 2048; t += 256) {
        float s = 0.f;
        for (int b = 0; b < 16; ++b) s += mv[b * 2048 + t];
        u[t] = s;
    }
    __syncthreads();
    for (int k = 0; k < 7; ++k) {
        float best = -3.4e38f; int bi = 0x7fffffff;
        for (int t = tid; t < 2048; t += 256)
            if (u[t] > best) { best = u[t]; bi = t; }
        rv[tid] = best; ri[tid] = bi;
        __syncthreads();
        for (int off = 128; off > 0; off >>= 1) {
            if (tid < off) {
                if (rv[tid + off] > rv[tid] ||
                    (rv[tid + off] == rv[tid] && ri[tid + off] < ri[tid])) {
                    rv[tid] = rv[tid + off]; ri[tid] = ri[tid + off];
                }
            }
            __syncthreads();
        }
        if (tid == 0) { ssel[k] = ri[0]; sel[k] = ri[0]; u[ri[0]] = -3.4e38f; }
        __syncthreads();
    }
    if (tid < 16) {
        float vals[7], mx = -3.4e38f;
        for (int k = 0; k < 7; ++k) { vals[k] = mv[tid * 2048 + ssel[k]]; mx = fmaxf(mx, vals[k]); }
        float se = 0.f;
        for (int k = 0; k < 7; ++k) { vals[k] = expf(vals[k] - mx); se += vals[k]; }
        for (int k = 0; k < 7; ++k) wsm[tid * 7 + k] = vals[k] / se;
    }
}

// agg[b,l,c] = sum_k w[b,k] * V[b,(l+sel[k])%L,c]
__global__ __launch_bounds__(256) void aggregate(
    const f16* __restrict__ V, const int* __restrict__ sel,
    const float* __restrict__ wsm, f16* __restrict__ agg)
{
    __shared__ int   sidx[7];
    __shared__ float sw[7];
    const int bl = blockIdx.x;
    const int b = bl >> 11, l = bl & 2047;
    if (threadIdx.x < 7) { sidx[threadIdx.x] = sel[threadIdx.x]; sw[threadIdx.x] = wsm[b * 7 + threadIdx.x]; }
    __syncthreads();
    const int c = threadIdx.x;
    float a0 = 0.f, a1 = 0.f;
#pragma unroll
    for (int k = 0; k < 7; ++k) {
        const int lk = (l + sidx[k]) & 2047;
        const f16* row = V + ((size_t)b * 2048 + lk) * 512;
        a0 += sw[k] * (float)row[c];
        a1 += sw[k] * (float)row[c + 256];
    }
    f16* orow = agg + ((size_t)b * 2048 + l) * 512;
    orow[c]       = (f16)a0;
    orow[c + 256] = (f16)a1;
}

extern "C" void kernel_launch(void* const* d_in, const int* in_sizes, int n_in,
                              void* d_out, int out_size, void* d_ws, size_t ws_size,
                              hipStream_t stream)
{
    (void)in_sizes; (void)n_in; (void)out_size; (void)ws_size;
    const float* queries = (const float*)d_in[0];
    const float* keys    = (const float*)d_in[1];
    const float* values  = (const float*)d_in[2];
    const float* Wq = (const float*)d_in[3];
    const float* bq = (const float*)d_in[4];
    const float* Wk = (const float*)d_in[5];
    const float* bk = (const float*)d_in[6];
    const float* Wv = (const float*)d_in[7];
    const float* bv = (const float*)d_in[8];
    const float* Wo = (const float*)d_in[9];
    const float* bo = (const float*)d_in[10];

    char* p = (char*)d_ws;
    f16*    QKt = (f16*)p;    p += 67108864;   // [1024][32768] f16: Q rows 0..511, K rows 512..1023
    f16*    Vb  = (f16*)p;    p += 33554432;   // V (b, l, c) f16
    f16*    agg = (f16*)p;    p += 33554432;   // aggregated V, f16
    f16*    wqh = (f16*)p;    p += 524288;     // Wq f16  (wqh+wkh = stacked Wqk, M=1024)
    f16*    wkh = (f16*)p;    p += 524288;     // Wk f16  (MUST stay adjacent to wqh)
    f16*    wvh = (f16*)p;    p += 524288;
    f16*    woh = (f16*)p;    p += 524288;
    float2* Sp  = (float2*)p; p += 8396800;    // 16 x 64 x 1025 cplx partials
    float2* Srd = (float2*)p; p += 131200;     // 16 x 1025 cplx reduced
    float*  mv  = (float*)p;  p += 131072;     // mean_value 16 x 2048
    int*    sel = (int*)p;    p += 256;        // top-7 lags
    float*  wsm = (float*)p;  p += 512;        // softmax weights 16 x 7
    f16*    Kt  = QKt + (size_t)512 * 32768;

    // weight conversion (1 MB each, one dispatch)
    cvt_weights<<<dim3(256, 4), 256, 0, stream>>>(Wq, Wk, Wv, Wo, wqh, wkh, wvh, woh);

    // QK^T = [Wq;Wk] * X^T; A = stacked f16 weights, B = queries/keys f32
    // DIRECT (reg-staged, convert-once). M=1024 (4 mt), N=32768 (128 nt).
    gemm_nt<0, 1, 1, 2, 7, 1, 1><<<512, 512, 0, stream>>>(
        wqh, queries, keys, QKt, 32768, bq, bk, nullptr);

    // V = values @ Wv^T; A = values f32 DIRECT, B = wvh f16. f16 out, +bv.
    gemm_nt<1, 0, 1, 7, 1, 2, 0><<<256, 512, 0, stream>>>(
        values, wvh, nullptr, Vb, 512, nullptr, nullptr, bv);

    // correlation spectra -> reduce -> mean_value -> selection -> aggregation
    fft_corr<<<dim3(64, 16), 256, 0, stream>>>(QKt, Kt, Sp);
    reduce_sp<<<dim3(16, 5), 256, 0, stream>>>(Sp, Srd);
    ifft_mean<<<16, 256, 0, stream>>>(Srd, mv);
    select_topk<<<1, 256, 0, stream>>>(mv, sel, wsm);
    aggregate<<<32768, 256, 0, stream>>>(Vb, sel, wsm, agg);

    // out = agg @ Wo^T + bo  -> d_out f32 (all-f16 operands, unchanged)
    gemm_nt<0, 0, 0, 7, 1, 2, 0><<<256, 512, 0, stream>>>(
        agg, woh, nullptr, (float*)d_out, 512, nullptr, nullptr, bo);
}

// Round 15
// 264.606 us; speedup vs baseline: 1.2033x; 1.0797x over previous
//
#include <hip/hip_runtime.h>

// AutoCorrelation attention (Autoformer) for B=16, L=2048, d=512, top_k=7.
// R1: XOR-swizzled GEMM LDS.  R2: FFT rewrite.  R3: 16x16x32 MFMA + XCD
// decode.  R4: f16 Q/K.  R5: merged QK GEMM + reduce_sp.  R6: reverted.
// R7: all-f16 GEMMs.  R8/R9: schedule variants — NEUTRAL.
// R10: coalesced C epilogue (WIN).  R11: 256x256 tiles.
// R12: cvt_inputs eliminated (f32 reg-staged convert-once in GEMMs) — WIN.
// R13: aggregate fused into O GEMM A-staging + fft_corr 4ch/block — FAILED:
//      stage_agg wrote a LINEAR LDS image (global[u] at LDS[u]) under a
//      swizzled reader.  R14: fixed — load global octet (tid&7), write LDS
//      octet uu=(tid&7)^(r&7), matching write_f16_slab's image exactly.

typedef _Float16 f16;
typedef _Float16 f16x8 __attribute__((ext_vector_type(8)));
typedef _Float16 f16x4 __attribute__((ext_vector_type(4)));
typedef float    f32x4 __attribute__((ext_vector_type(4)));

#define PSI(i) ((i) + ((i) >> 3))          // z anti-conflict pad (2048 -> 2304)
#define TWI(j) ((j) + ((j) >> 4))          // tw anti-conflict pad (1024 -> 1088)

__device__ __forceinline__ float2 f2add(float2 a, float2 b) { return make_float2(a.x + b.x, a.y + b.y); }
__device__ __forceinline__ float2 f2sub(float2 a, float2 b) { return make_float2(a.x - b.x, a.y - b.y); }
__device__ __forceinline__ float2 cmul(float2 a, float2 b)  { return make_float2(a.x * b.x - a.y * b.y, a.x * b.y + a.y * b.x); }

// ---------------- conversion: f32 -> f16 (weights only) ---------------------
__global__ __launch_bounds__(256) void cvt_weights(
    const float* __restrict__ w0, const float* __restrict__ w1,
    const float* __restrict__ w2, const float* __restrict__ w3,
    f16* __restrict__ o0, f16* __restrict__ o1, f16* __restrict__ o2, f16* __restrict__ o3)
{
    const float* src = (blockIdx.y == 0) ? w0 : (blockIdx.y == 1) ? w1 : (blockIdx.y == 2) ? w2 : w3;
    f16*         dst = (blockIdx.y == 0) ? o0 : (blockIdx.y == 1) ? o1 : (blockIdx.y == 2) ? o2 : o3;
    const int i = blockIdx.x * 256 + threadIdx.x;
    float4 val = ((const float4*)src)[i];
    f16x4 h = { (f16)val.x, (f16)val.y, (f16)val.z, (f16)val.w };
    ((f16x4*)dst)[i] = h;
}

// ---------------- GEMM staging ----------------------------------------------
// LDS image per 256-row x 64-col slab (32 KB f16): LDS[rr][uu] holds global
// 8-elem octet (uu ^ (rr&7)) of row rr — read side XORs the same key.
__device__ __forceinline__ void stage_f16(const f16* __restrict__ G, int row0, int k0,
                                          f16* __restrict__ lds, int tid)
{
#pragma unroll
    for (int q = 0; q < 4; ++q) {
        const int r = q * 64 + (tid >> 3);
        const int u = (tid & 7) ^ ((tid >> 3) & 7);
        const f16* g = G + (size_t)(row0 + r) * 512 + k0 + u * 8;
        f16* d = lds + q * 4096 + (tid >> 6) * 512;     // wave-uniform base
        __builtin_amdgcn_global_load_lds(
            (const __attribute__((address_space(1))) void*)g,
            (__attribute__((address_space(3))) void*)d, 16, 0, 0);
    }
}

// f32 source, step 1: contiguous 32B/thread loads into regs (8 float4).
__device__ __forceinline__ void load_f32_slab(const float* __restrict__ G, int row0, int k0,
                                              int tid, float4* __restrict__ rg)
{
#pragma unroll
    for (int q = 0; q < 4; ++q) {
        const float* g = G + (size_t)(row0 + q * 64 + (tid >> 3)) * 512 + k0 + (tid & 7) * 8;
        rg[2 * q]     = *(const float4*)g;
        rg[2 * q + 1] = *(const float4*)(g + 4);
    }
}
// f32 source, step 2 (after compute): cvt once + swizzled ds_write_b128.
__device__ __forceinline__ void write_f16_slab(f16* __restrict__ lds, int tid,
                                               const float4* __restrict__ rg)
{
#pragma unroll
    for (int q = 0; q < 4; ++q) {
        float4 a = rg[2 * q], b = rg[2 * q + 1];
        f16x8 h = { (f16)a.x, (f16)a.y, (f16)a.z, (f16)a.w,
                    (f16)b.x, (f16)b.y, (f16)b.z, (f16)b.w };
        const int uu = (tid & 7) ^ ((tid >> 3) & 7);
        *(f16x8*)(lds + q * 4096 + (tid >> 3) * 64 + (uu << 3)) = h;
    }
}

// fused-aggregate A slab: A[l][c] = sum_k w[k] * V[b][(l+sel[k])&2047][c].
// R14 FIX: gather GLOBAL octet (tid&7); write LDS octet uu=(tid&7)^(r&7) —
// identical image to write_f16_slab (R13 wrote global[u] at LDS[u]: linear
// image under swizzled reader -> scrambled A).
__device__ __forceinline__ void stage_agg(const f16* __restrict__ Vb_, int l0, int k0,
                                          const int* __restrict__ ssel, const float* __restrict__ sw,
                                          f16* __restrict__ lds, int tid)
{
    const f16* base = Vb_ + k0 + (tid & 7) * 8;     // global octet = tid&7
#pragma unroll
    for (int q = 0; q < 4; ++q) {
        const int l  = l0 + q * 64 + (tid >> 3);
        const int uu = (tid & 7) ^ ((tid >> 3) & 7);
        float a0 = 0.f, a1 = 0.f, a2 = 0.f, a3 = 0.f, a4 = 0.f, a5 = 0.f, a6 = 0.f, a7 = 0.f;
#pragma unroll
        for (int k = 0; k < 7; ++k) {
            const int lk = (l + ssel[k]) & 2047;
            f16x8 v = *(const f16x8*)(base + (size_t)lk * 512);
            const float w = sw[k];
            a0 += w * (float)v[0]; a1 += w * (float)v[1];
            a2 += w * (float)v[2]; a3 += w * (float)v[3];
            a4 += w * (float)v[4]; a5 += w * (float)v[5];
            a6 += w * (float)v[6]; a7 += w * (float)v[7];
        }
        f16x8 h = { (f16)a0, (f16)a1, (f16)a2, (f16)a3, (f16)a4, (f16)a5, (f16)a6, (f16)a7 };
        *(f16x8*)(lds + q * 4096 + (tid >> 3) * 64 + (uu << 3)) = h;
    }
}

// ---------------- NT GEMM: C[M,N] = A * B^T (+bias), f16 16x16x32 MFMA ------
// BM = BN = 256, BK = 64, K = 512. 8 waves, per-wave 128x64 output.
// 2-buffer LDS (128 KB), stage-ahead schedule; f32 operands reg-staged
// (convert-once); AGG=1 gathers A from V via sel/wsm (fused aggregate).
// Coalesced swizzled-LDS epilogue (R10/R11).
template<int AF32, int BF32, int AGG, int F16OUT, int MT_L2, int NT_L2, int SWZ, int SPLITB>
__global__ __launch_bounds__(512, 2) void gemm_nt(
    const void* __restrict__ A0v, const void* __restrict__ B0v, const void* __restrict__ B1v,
    void* __restrict__ Cout, int N,
    const float* __restrict__ bias_q, const float* __restrict__ bias_k,
    const float* __restrict__ bias_col,
    const int* __restrict__ selp, const float* __restrict__ wsmp)
{
    constexpr int BM = 256, BN = 256, NKT = 8;
    constexpr int ESZ = F16OUT ? 2 : 4;

    __shared__ __align__(16) char smem[131072];         // 2 x (32K A + 32K B) f16
    f16* smA = (f16*)smem;                              // [2][BM*64]
    f16* smB = (f16*)smem + 2 * BM * 64;                // [2][BN*64]

    const int tid  = threadIdx.x;
    const int wave = tid >> 6, lane = tid & 63;

    int mt, nt;
    if (SWZ == 1) {
        const int xcd = blockIdx.x & 7, slot = blockIdx.x >> 3;
        mt = slot & ((1 << MT_L2) - 1);
        nt = (xcd << (NT_L2 - 3)) | (slot >> MT_L2);
    } else if (SWZ == 2) {
        const int xcd = blockIdx.x & 7, slot = blockIdx.x >> 3;
        nt = slot & ((1 << NT_L2) - 1);
        mt = (xcd << (MT_L2 - 3)) | (slot >> NT_L2);
    } else {
        nt = blockIdx.x & ((1 << NT_L2) - 1);
        mt = blockIdx.x >> NT_L2;
    }
    const int m0 = mt * BM, n0 = nt * BN;

    const bool useB1 = SPLITB && (mt >= (1 << (MT_L2 - 1)));
    const void* Bgv = useB1 ? B1v : B0v;
    const float* brow = SPLITB
        ? (useB1 ? bias_k - (1 << (MT_L2 - 1)) * BM : bias_q)
        : bias_q;

    const f16*   Ah = (const f16*)A0v;
    const float* Af = (const float*)A0v;
    const f16*   Bh = (const f16*)Bgv;
    const float* Bf = (const float*)Bgv;

    // fused-aggregate state (AGG only): block rows live in one batch
    int   ssel[7];
    float sw[7];
    const f16* Vbase = nullptr;
    int l0 = 0;
    if (AGG) {
        const int b = m0 >> 11;                 // 2048 rows per batch
        l0 = m0 & 2047;
        Vbase = Ah + (size_t)b * 2048 * 512;
#pragma unroll
        for (int k = 0; k < 7; ++k) { ssel[k] = selp[k]; sw[k] = wsmp[b * 7 + k]; }
    }

    f32x4 acc[8][4];
#pragma unroll
    for (int m = 0; m < 8; ++m)
#pragma unroll
        for (int n = 0; n < 4; ++n) acc[m][n] = (f32x4){0.f, 0.f, 0.f, 0.f};

    const int fr = lane & 15;
    const int kg = (lane >> 4) * 8;          // k-group base within 32-wide K step
    const int rowm = fr & 7;                 // read-side swizzle key
    const int wr = wave >> 2;                // wave row (0..1), 128 rows each
    const int wc = wave & 3;                 // wave col (0..3), 64 cols each
    const int warow = wr * 128 + fr;
    const int wbrow = wc * 64 + fr;

    auto compute = [&](const f16* __restrict__ Ab, const f16* __restrict__ Bb) {
#pragma unroll
        for (int k2 = 0; k2 < 2; ++k2) {
            const int kb = k2 * 32 + kg;
            const int col = ((kb >> 3) ^ rowm) << 3;
            f16x8 af[8], bf[4];
#pragma unroll
            for (int m = 0; m < 8; ++m) af[m] = *(const f16x8*)&Ab[(warow + m * 16) * 64 + col];
#pragma unroll
            for (int n = 0; n < 4; ++n) bf[n] = *(const f16x8*)&Bb[(wbrow + n * 16) * 64 + col];
#pragma unroll
            for (int m = 0; m < 8; ++m)
#pragma unroll
                for (int n = 0; n < 4; ++n)
                    acc[m][n] = __builtin_amdgcn_mfma_f32_16x16x32_f16(af[m], bf[n], acc[m][n], 0, 0, 0);
        }
    };

    float4 ra[8], rb[8];

    // prologue: slab 0 staged completely
    if (AGG)       stage_agg(Vbase, l0, 0, ssel, sw, smA, tid);
    else if (AF32) { load_f32_slab(Af, m0, 0, tid, ra); write_f16_slab(smA, tid, ra); }
    else           stage_f16(Ah, m0, 0, smA, tid);
    if (BF32) { load_f32_slab(Bf, n0, 0, tid, rb); write_f16_slab(smB, tid, rb); }
    else      stage_f16(Bh, n0, 0, smB, tid);
    asm volatile("s_waitcnt vmcnt(0) lgkmcnt(0)" ::: "memory");
    __builtin_amdgcn_s_barrier();

#pragma unroll 1
    for (int kk = 0; kk < NKT; ++kk) {
        const int cur = kk & 1;
        if (kk < NKT - 1) {
            const int k0 = (kk + 1) * 64;
            if (AGG)       stage_agg(Vbase, l0, k0, ssel, sw, smA + (cur ^ 1) * BM * 64, tid);
            else if (AF32) load_f32_slab(Af, m0, k0, tid, ra);     // issue early
            else           stage_f16(Ah, m0, k0, smA + (cur ^ 1) * BM * 64, tid);
            if (BF32) load_f32_slab(Bf, n0, k0, tid, rb);
            else      stage_f16(Bh, n0, k0, smB + (cur ^ 1) * BN * 64, tid);
        }
        compute(smA + cur * BM * 64, smB + cur * BN * 64);          // hides load latency
        if (kk < NKT - 1) {
            if (AF32) write_f16_slab(smA + (cur ^ 1) * BM * 64, tid, ra);   // write late
            if (BF32) write_f16_slab(smB + (cur ^ 1) * BN * 64, tid, rb);
        }
        asm volatile("s_waitcnt vmcnt(0) lgkmcnt(0)" ::: "memory");
        __builtin_amdgcn_s_barrier();
    }

    // ---- epilogue: acc -> swizzled LDS C tile -> linear 16B stores ----
    constexpr int L     = F16OUT ? 3 : 2;          // elems-per-16B log2
    constexpr int CPR   = (BN * ESZ) / 16;         // 16B chunks per row
    constexpr int HROWS = F16OUT ? 256 : 128;      // rows per epilogue pass
    constexpr int NH    = F16OUT ? 1 : 2;
#pragma unroll 1
    for (int h = 0; h < NH; ++h) {
        __syncthreads();
        if (F16OUT || wr == h) {
            const int lr0 = wr * 128 + ((lane >> 4) << 2);
#pragma unroll
            for (int m = 0; m < 8; ++m)
#pragma unroll
                for (int n = 0; n < 4; ++n) {
                    const int col = wc * 64 + n * 16 + fr;
                    const float bc = bias_col ? bias_col[n0 + col] : 0.f;
#pragma unroll
                    for (int j = 0; j < 4; ++j) {
                        const int row  = lr0 + m * 16 + j;
                        const int rl   = row - h * HROWS * (F16OUT ? 0 : 1);
                        const int scol = ((((col >> L) ^ (row & 7)) << L) | (col & ((1 << L) - 1)));
                        float v = acc[m][n][j] + bc + (brow ? brow[m0 + row] : 0.f);
                        if (F16OUT) ((f16*)smem)[row * BN + scol] = (f16)v;
                        else        ((float*)smem)[rl * BN + scol] = v;
                    }
                }
        }
        __syncthreads();
        const int chunks = HROWS * CPR;
#pragma unroll 1
        for (int i = tid; i < chunks; i += 512) {
            const int rl  = i / CPR;
            const int u   = i % CPR;
            const int row = h * HROWS + rl;
            int4 vv = *(const int4*)(smem + (rl * CPR + (u ^ (row & 7))) * 16);
            *(int4*)((char*)Cout + ((size_t)(m0 + row) * N + n0) * ESZ + u * 16) = vv;
        }
    }
}

// ---------------- 2048-pt FFT: fused double radix-2 DIF passes --------------
template<int S>
__device__ __forceinline__ void fft_pass2(float2* __restrict__ z, const float2* __restrict__ tw, int tid)
{
    constexpr int m = 1024 >> S;
    constexpr int h = m >> 1;
#pragma unroll
    for (int rep = 0; rep < 2; ++rep) {
        const int idx = tid + rep * 256;
        const int j2  = idx & (h - 1);
        const int blk = idx >> (9 - S);
        const int i   = (blk << (11 - S)) + j2;
        const float2 w1 = tw[TWI(j2 << S)];
        const float2 w2 = tw[TWI(j2 << (S + 1))];
        float2 a = z[PSI(i)], b = z[PSI(i + h)], c = z[PSI(i + m)], d = z[PSI(i + m + h)];
        float2 a1 = f2add(a, c);
        float2 c1 = cmul(f2sub(a, c), w1);
        float2 b1 = f2add(b, d);
        float2 t0 = cmul(f2sub(b, d), w1);
        float2 d1 = make_float2(t0.y, -t0.x);            // * (-i)  (w_{j+h} = -i*w_j)
        z[PSI(i)]         = f2add(a1, b1);
        z[PSI(i + h)]     = cmul(f2sub(a1, b1), w2);
        z[PSI(i + m)]     = f2add(c1, d1);
        z[PSI(i + m + h)] = cmul(f2sub(c1, d1), w2);
    }
    __syncthreads();
}

__device__ __forceinline__ void fft_tail_scatter(float2* __restrict__ z, int tid)
{
    float2 v[8];
    const int p0 = tid * 8;
#pragma unroll
    for (int e = 0; e < 8; ++e) v[e] = z[PSI(p0 + e)];
    __syncthreads();
    constexpr float RS = 0.70710678118654752f;
    const float2 W8[4] = { {1.f, 0.f}, {RS, -RS}, {0.f, -1.f}, {-RS, -RS} };
#pragma unroll
    for (int e = 0; e < 4; ++e) {
        float2 t = f2sub(v[e], v[e + 4]);
        v[e]     = f2add(v[e], v[e + 4]);
        v[e + 4] = cmul(t, W8[e]);
    }
#pragma unroll
    for (int base = 0; base < 8; base += 4) {
        float2 t0 = f2sub(v[base], v[base + 2]);
        v[base]     = f2add(v[base], v[base + 2]);
        v[base + 2] = t0;
        float2 t1 = f2sub(v[base + 1], v[base + 3]);
        v[base + 1] = f2add(v[base + 1], v[base + 3]);
        v[base + 3] = make_float2(t1.y, -t1.x);
    }
#pragma unroll
    for (int base = 0; base < 8; base += 2) {
        float2 t = f2sub(v[base], v[base + 1]);
        v[base]     = f2add(v[base], v[base + 1]);
        v[base + 1] = t;
    }
    const int br8t = (int)(__brev((unsigned)tid) >> 24);
    const int BR3[8] = {0, 4, 2, 6, 1, 5, 3, 7};
#pragma unroll
    for (int e = 0; e < 8; ++e) {
        const int f = br8t + (BR3[e] << 8);
        z[PSI(f)] = v[e];
    }
    __syncthreads();
}

__device__ __forceinline__ void fft2048_natural(float2* __restrict__ z, const float2* __restrict__ tw, int tid)
{
    fft_pass2<0>(z, tw, tid);
    fft_pass2<2>(z, tw, tid);
    fft_pass2<4>(z, tw, tid);
    fft_pass2<6>(z, tw, tid);
    fft_tail_scatter(z, tid);   // z now holds Z[f] at natural f (PSI-mapped)
}

__device__ __forceinline__ void fill_tw(float2* __restrict__ tw, int tid)
{
    for (int j = tid; j < 1024; j += 256) {
        float sv, cv;
        sincospif(-(float)j * (1.0f / 1024.0f), &sv, &cv);   // e^{-2 pi i j / 2048}
        tw[TWI(j)] = make_float2(cv, sv);
    }
}

// 4 channels/block (2048 blocks, 6/CU LDS residency): z = q + i*k packed FFT;
// S_c = Q*conj(K) accumulated in registers; Hermitian half written to Sp.
__global__ __launch_bounds__(256) void fft_corr(
    const f16* __restrict__ Qt, const f16* __restrict__ Kt,
    float2* __restrict__ Sp)
{
    __shared__ float2 z[2304];
    __shared__ float2 tw[1088];
    const int tid = threadIdx.x;
    const int grp = blockIdx.x;   // 0..127 channel group (4 ch each)
    const int b   = blockIdx.y;   // 0..15 batch

    fill_tw(tw, tid);
    float2 racc[5];
#pragma unroll
    for (int r = 0; r < 5; ++r) racc[r] = make_float2(0.f, 0.f);
    __syncthreads();

    for (int ch = 0; ch < 4; ++ch) {
        const int c = grp * 4 + ch;
        const f16x8* qr = (const f16x8*)(Qt + ((size_t)c * 16 + b) * 2048);
        const f16x8* kr = (const f16x8*)(Kt + ((size_t)c * 16 + b) * 2048);
        f16x8 qv = qr[tid], kv = kr[tid];
        const int e0 = tid * 8;
#pragma unroll
        for (int j = 0; j < 8; ++j)
            z[PSI(e0 + j)] = make_float2((float)qv[j], (float)kv[j]);
        __syncthreads();
        fft2048_natural(z, tw, tid);
#pragma unroll
        for (int r = 0; r < 5; ++r) {
            const int f = tid + (r << 8);
            if (f <= 1024) {
                const int pf = (2048 - f) & 2047;
                float2 Zf  = z[PSI(f)];
                float2 Zc0 = z[PSI(pf)];
                float qx = 0.5f * (Zf.x + Zc0.x), qy = 0.5f * (Zf.y - Zc0.y);
                float dx = Zf.x - Zc0.x,          dy = Zf.y + Zc0.y;
                float kx = 0.5f * dy,             ky = -0.5f * dx;   // K = -i*D/2
                racc[r].x += qx * kx + qy * ky;                      // Q*conj(K)
                racc[r].y += qy * kx - qx * ky;
            }
        }
        __syncthreads();
    }
    float2* out = Sp + ((size_t)b * 128 + grp) * 1025;
#pragma unroll
    for (int r = 0; r < 5; ++r) {
        const int f = tid + (r << 8);
        if (f <= 1024) out[f] = racc[r];
    }
}

// fixed-order sum of the 128 per-group spectra -> Sred[b][f]
__global__ __launch_bounds__(256) void reduce_sp(
    const float2* __restrict__ Sp, float2* __restrict__ Sred)
{
    const int b = blockIdx.x;
    const int f = blockIdx.y * 256 + threadIdx.x;
    if (f > 1024) return;
    const float2* base = Sp + (size_t)b * 128 * 1025 + f;
    float sx = 0.f, sy = 0.f;
#pragma unroll 8
    for (int g = 0; g < 128; ++g) {
        float2 p = base[(size_t)g * 1025];
        sx += p.x; sy += p.y;
    }
    Sred[b * 1025 + f] = make_float2(sx, sy);
}

// rebuild full spectrum from Hermitian half, inverse FFT via conj trick
// (same natural-order forward FFT), write mean_value.
__global__ __launch_bounds__(256) void ifft_mean(
    const float2* __restrict__ Sred, float* __restrict__ mv)
{
    __shared__ float2 z[2304];
    __shared__ float2 tw[1088];
    const int tid = threadIdx.x;
    const int b   = blockIdx.x;
    fill_tw(tw, tid);
#pragma unroll
    for (int r = 0; r < 5; ++r) {
        const int f = tid + (r << 8);
        if (f <= 1024) {
            float2 s = Sred[b * 1025 + f];
            z[PSI(f)] = make_float2(s.x, -s.y);                     // conj(S[f])
            if (f >= 1 && f <= 1023)
                z[PSI(2048 - f)] = make_float2(s.x, s.y);           // conj(S[2048-f]) = S[f]
        }
    }
    __syncthreads();
    fft2048_natural(z, tw, tid);
    const float scale = 1.0f / (2048.0f * 512.0f);  // irfft 1/N and channel mean
    for (int t = tid; t < 2048; t += 256)
        mv[(size_t)b * 2048 + t] = z[PSI(t)].x * scale;
}

// top-7 lags of batch-mean corr + per-batch softmax weights. One block.
__global__ __launch_bounds__(256) void select_topk(
    const float* __restrict__ mv, int* __restrict__ sel, float* __restrict__ wsm)
{
    __shared__ float u[2048];
    __shared__ float rv[256];
    __shared__ int   ri[256];
    __shared__ int   ssel[7];
    const int tid = threadIdx.x;
    for (int t = tid; t < 2048; t += 256) {
        float s = 0.f;
        for (int b = 0; b < 16; ++b) s += mv[b * 2048 + t];
        u[t] = s;
    }
    __syncthreads();
    for (int k = 0; k < 7; ++k) {
        float best = -3.4e38f; int bi = 0x7fffffff;
        for (int t = tid; t < 2048; t += 256)
            if (u[t] > best) { best = u[t]; bi = t; }
        rv[tid] = best; ri[tid] = bi;
        __syncthreads();
        for (int off = 128; off > 0; off >>= 1) {
            if (tid < off) {
                if (rv[tid + off] > rv[tid] ||
                    (rv[tid + off] == rv[tid] && ri[tid + off] < ri[tid])) {
                    rv[tid] = rv[tid + off]; ri[tid] = ri[tid + off];
                }
            }
            __syncthreads();
        }
        if (tid == 0) { ssel[k] = ri[0]; sel[k] = ri[0]; u[ri[0]] = -3.4e38f; }
        __syncthreads();
    }
    if (tid < 16) {
        float vals[7], mx = -3.4e38f;
        for (int k = 0; k < 7; ++k) { vals[k] = mv[tid * 2048 + ssel[k]]; mx = fmaxf(mx, vals[k]); }
        float se = 0.f;
        for (int k = 0; k < 7; ++k) { vals[k] = expf(vals[k] - mx); se += vals[k]; }
        for (int k = 0; k < 7; ++k) wsm[tid * 7 + k] = vals[k] / se;
    }
}

extern "C" void kernel_launch(void* const* d_in, const int* in_sizes, int n_in,
                              void* d_out, int out_size, void* d_ws, size_t ws_size,
                              hipStream_t stream)
{
    (void)in_sizes; (void)n_in; (void)out_size; (void)ws_size;
    const float* queries = (const float*)d_in[0];
    const float* keys    = (const float*)d_in[1];
    const float* values  = (const float*)d_in[2];
    const float* Wq = (const float*)d_in[3];
    const float* bq = (const float*)d_in[4];
    const float* Wk = (const float*)d_in[5];
    const float* bk = (const float*)d_in[6];
    const float* Wv = (const float*)d_in[7];
    const float* bv = (const float*)d_in[8];
    const float* Wo = (const float*)d_in[9];
    const float* bo = (const float*)d_in[10];

    char* p = (char*)d_ws;
    f16*    QKt = (f16*)p;    p += 67108864;   // [1024][32768] f16: Q rows 0..511, K rows 512..1023
    f16*    Vb  = (f16*)p;    p += 33554432;   // V (b, l, c) f16
    f16*    wqh = (f16*)p;    p += 524288;     // Wq f16  (wqh+wkh = stacked Wqk, M=1024)
    f16*    wkh = (f16*)p;    p += 524288;     // Wk f16  (MUST stay adjacent to wqh)
    f16*    wvh = (f16*)p;    p += 524288;
    f16*    woh = (f16*)p;    p += 524288;
    float2* Sp  = (float2*)p; p += 16793600;   // 16 x 128 x 1025 cplx partials
    float2* Srd = (float2*)p; p += 131200;     // 16 x 1025 cplx reduced
    float*  mv  = (float*)p;  p += 131072;     // mean_value 16 x 2048
    int*    sel = (int*)p;    p += 256;        // top-7 lags
    float*  wsm = (float*)p;  p += 512;        // softmax weights 16 x 7
    f16*    Kt  = QKt + (size_t)512 * 32768;

    // weight conversion (1 MB each, one dispatch)
    cvt_weights<<<dim3(256, 4), 256, 0, stream>>>(Wq, Wk, Wv, Wo, wqh, wkh, wvh, woh);

    // QK^T = [Wq;Wk] * X^T; A = stacked f16 weights, B = queries/keys f32
    // DIRECT (reg-staged, convert-once). M=1024 (4 mt), N=32768 (128 nt).
    gemm_nt<0, 1, 0, 1, 2, 7, 1, 1><<<512, 512, 0, stream>>>(
        wqh, queries, keys, QKt, 32768, bq, bk, nullptr, nullptr, nullptr);

    // V = values @ Wv^T; A = values f32 DIRECT, B = wvh f16. f16 out, +bv.
    gemm_nt<1, 0, 0, 1, 7, 1, 2, 0><<<256, 512, 0, stream>>>(
        values, wvh, nullptr, Vb, 512, nullptr, nullptr, bv, nullptr, nullptr);

    // correlation spectra -> reduce -> mean_value -> selection
    fft_corr<<<dim3(128, 16), 256, 0, stream>>>(QKt, Kt, Sp);
    reduce_sp<<<dim3(16, 5), 256, 0, stream>>>(Sp, Srd);
    ifft_mean<<<16, 256, 0, stream>>>(Srd, mv);
    select_topk<<<1, 256, 0, stream>>>(mv, sel, wsm);

    // out = aggregate(V) @ Wo^T + bo  -> d_out f32, aggregation FUSED into
    // the A-staging (7-lag weighted gather from Vb, L2-resident per batch).
    gemm_nt<0, 0, 1, 0, 7, 1, 2, 0><<<256, 512, 0, stream>>>(
        Vb, woh, nullptr, (float*)d_out, 512, nullptr, nullptr, bo, sel, wsm);
}